// Round 17
// baseline (366.034 us; speedup 1.0000x reference)
//
#include <hip/hip_runtime.h>
#include <hip/hip_bf16.h>

typedef short s16x8 __attribute__((ext_vector_type(8)));
typedef float f32x4 __attribute__((ext_vector_type(4)));
typedef float f32x16 __attribute__((ext_vector_type(16)));
typedef unsigned u32;
typedef unsigned u32x4 __attribute__((ext_vector_type(4)));
typedef unsigned short u16;

#define DMODEL 2048
#define NH     16
#define NKV    4
#define HD     128
#define NB     4
#define SS     2048

static __device__ __forceinline__ u16 f2bf(float f) {
  unsigned u = __builtin_bit_cast(unsigned, f);
  u += 0x7fffu + ((u >> 16) & 1u);          // RNE
  return (u16)(u >> 16);
}
static __device__ __forceinline__ float bf2f(u16 h) {
  unsigned u = ((unsigned)h) << 16;
  return __builtin_bit_cast(float, u);
}
static __device__ __forceinline__ u32 packbf(float a, float b) {
  return (u32)f2bf(a) | ((u32)f2bf(b) << 16);
}

typedef const __attribute__((address_space(1))) void* gas_p;
typedef __attribute__((address_space(3))) void* las_p;
#define GLOAD16(g, l) __builtin_amdgcn_global_load_lds((gas_p)(const void*)(g), (las_p)(void*)(l), 16, 0, 0)

// ---------------------------------------------------------------- cast: f32 -> bf16
__global__ void cast_all(const float* __restrict__ x,  const float* __restrict__ wq,
                         const float* __restrict__ wk, const float* __restrict__ wv,
                         const float* __restrict__ wo,
                         u16* __restrict__ xb, u16* __restrict__ wqkv, u16* __restrict__ wob)
{
  long gid = (long)blockIdx.x * 256 + threadIdx.x;
  long i = gid * 4;
  const float* src; u16* dst; long off;
  if (i < 16777216L)       { src = x;  dst = xb;             off = i; }
  else if (i < 20971520L)  { src = wq; dst = wqkv;           off = i - 16777216L; }
  else if (i < 22020096L)  { src = wk; dst = wqkv + 4194304; off = i - 20971520L; }
  else if (i < 23068672L)  { src = wv; dst = wqkv + 5242880; off = i - 22020096L; }
  else                     { src = wo; dst = wob;            off = i - 23068672L; }
  float4 v = *(const float4*)(src + off);
  ushort4 o;
  o.x = f2bf(v.x); o.y = f2bf(v.y); o.z = f2bf(v.z); o.w = f2bf(v.w);
  *(ushort4*)(dst + off) = o;
}

// ---------------------------------------------------------------- epilogue scatter (shared)
static __device__ __forceinline__ void epi_store(int EPI, int row, int col, float v,
    u16* __restrict__ Oq, u16* __restrict__ Ok, u16* __restrict__ Ov, float* __restrict__ Of)
{
  if (EPI == 0) {
    int b = row >> 11, s = row & 2047;
    u16 hv = f2bf(v);
    if (col < 2048) {
      int hh = col >> 7, d = col & 127;
      Oq[(((long)(b * NH + hh)) * SS + s) * HD + d] = hv;
    } else if (col < 2560) {
      int c2 = col - 2048, kh = c2 >> 7, d = c2 & 127;
      Ok[(((long)(b * NKV + kh)) * SS + s) * HD + d] = hv;
    } else {
      int c2 = col - 2560, kh = c2 >> 7, d = c2 & 127;
      Ov[(((long)(b * NKV + kh)) * HD + d) * SS + s] = hv;   // V transposed [d][s]
    }
  } else {
    Of[(long)row * DMODEL + col] = v;
  }
}

// ---------------------------------------------------------------- GEMM 128x256 (KV) — R10-verified, + col offset
template<int NTC, int COFF>
__global__ __launch_bounds__(512) void gemm128(
    const u16* __restrict__ A, const u16* __restrict__ Bm, int K,
    u16* __restrict__ Oq, u16* __restrict__ Ok, u16* __restrict__ Ov)
{
  __shared__ __align__(16) u16 lds[2][24576];     // 48KB each
  const int tid = threadIdx.x, l = tid & 63, w = tid >> 6;
  const int lg = l >> 4, lr = l & 15;
  const int wm = w >> 2, wn = w & 3;

  const int nwg = NTC * 64;
  const int cpx = nwg >> 3;
  const int bid = blockIdx.x;
  const int swz = (bid & 7) * cpx + (bid >> 3);   // bijective: nwg % 8 == 0
  const int by = swz / NTC, bx = swz % NTC;
  const int rowBase = by * 128, colBase = bx * 256;

  const int rloc = w * 8 + (l >> 3);
  const int cgo  = ((l & 7) ^ (l >> 3)) * 8;
  const u16* gp[6];
#pragma unroll
  for (int seg = 0; seg < 6; seg++) {
    if (seg < 2) gp[seg] = A  + (long)(rowBase + seg * 64 + rloc) * K + cgo;
    else         gp[seg] = Bm + (long)(colBase + (seg - 2) * 64 + rloc) * K + cgo;
  }

  f32x4 acc[4][4] = {};

  auto stage = [&](int buf) {
    char* base = (char*)&lds[buf][0];
#pragma unroll
    for (int seg = 0; seg < 6; seg++)
      GLOAD16(gp[seg], base + seg * 8192 + w * 1024);
  };

  const int NKT = K >> 6;
  stage(0);
#pragma unroll
  for (int seg = 0; seg < 6; seg++) gp[seg] += 64;
  asm volatile("s_waitcnt vmcnt(0)" ::: "memory");
  __builtin_amdgcn_s_barrier();

  for (int kt = 0; kt < NKT; kt++) {
    const int cur = kt & 1;
    if (kt + 1 < NKT) {
      stage(cur ^ 1);
#pragma unroll
      for (int seg = 0; seg < 6; seg++) gp[seg] += 64;
      asm volatile("s_waitcnt vmcnt(6)" ::: "memory");
    } else {
      asm volatile("s_waitcnt vmcnt(0)" ::: "memory");
    }
    __builtin_amdgcn_s_barrier();
    asm volatile("" ::: "memory");

    const char* ab = (const char*)&lds[cur][0] + wm * 8192;
    const char* bb = (const char*)&lds[cur][0] + (2 + wn) * 8192;
    s16x8 af[4][2], bfr[4][2];
#pragma unroll
    for (int m = 0; m < 4; m++)
#pragma unroll
      for (int ks = 0; ks < 2; ks++) {
        int rr = m * 16 + lr;
        int c = ks * 4 + lg;
        af[m][ks]  = *(const s16x8*)(ab + rr * 128 + ((c ^ (rr & 7)) * 16));
        bfr[m][ks] = *(const s16x8*)(bb + rr * 128 + ((c ^ (rr & 7)) * 16));
      }
    __builtin_amdgcn_s_setprio(1);
#pragma unroll
    for (int ks = 0; ks < 2; ks++)
#pragma unroll
      for (int m = 0; m < 4; m++)
#pragma unroll
        for (int n = 0; n < 4; n++)
          acc[m][n] = __builtin_amdgcn_mfma_f32_16x16x32_bf16(af[m][ks], bfr[n][ks], acc[m][n], 0, 0, 0);
    __builtin_amdgcn_s_setprio(0);
    asm volatile("" ::: "memory");
    __builtin_amdgcn_s_barrier();
    asm volatile("" ::: "memory");
  }

#pragma unroll
  for (int m = 0; m < 4; m++)
#pragma unroll
    for (int n = 0; n < 4; n++)
#pragma unroll
      for (int r = 0; r < 4; r++)
        epi_store(0, rowBase + wm * 64 + m * 16 + lg * 4 + r,
                  COFF + colBase + wn * 64 + n * 16 + lr, acc[m][n][r], Oq, Ok, Ov, nullptr);
}

// ---------------------------------------------------------------- GEMM 256x256 — R9 4-phase, unchanged
#define GPHASE(MQ, STG, WAIT)                                               \
  {                                                                         \
    s16x8 af[2][2];                                                         \
    _Pragma("unroll") for (int j = 0; j < 2; j++)                           \
      _Pragma("unroll") for (int ks = 0; ks < 2; ks++) {                    \
        int rr = (MQ) * 32 + j * 16 + lr;                                   \
        int c = ks * 4 + lg;                                                \
        af[j][ks] = *(const s16x8*)(ab + rr * 128 + ((c ^ (rr & 7)) * 16)); \
      }                                                                     \
    STG;                                                                    \
    WAIT;                                                                   \
    asm volatile("" ::: "memory");                                          \
    __builtin_amdgcn_s_barrier();                                           \
    asm volatile("" ::: "memory");                                          \
    __builtin_amdgcn_s_setprio(1);                                          \
    _Pragma("unroll") for (int ks = 0; ks < 2; ks++)                        \
      _Pragma("unroll") for (int j = 0; j < 2; j++)                         \
        _Pragma("unroll") for (int n = 0; n < 4; n++)                       \
          acc[(MQ) * 2 + j][n] = __builtin_amdgcn_mfma_f32_16x16x32_bf16(   \
              af[j][ks], bfr[n][ks], acc[(MQ) * 2 + j][n], 0, 0, 0);        \
    __builtin_amdgcn_s_setprio(0);                                          \
    asm volatile("" ::: "memory");                                          \
    __builtin_amdgcn_s_barrier();                                           \
    asm volatile("" ::: "memory");                                          \
  }

template<int NT, int EPI>
__global__ __launch_bounds__(512) void gemm256(
    const u16* __restrict__ A, const u16* __restrict__ Bm, int K,
    u16* __restrict__ Oq, u16* __restrict__ Ok, u16* __restrict__ Ov, float* __restrict__ Of)
{
  __shared__ __align__(16) u16 lds[2][32768];     // 2 x 64KB
  const int tid = threadIdx.x, l = tid & 63, w = tid >> 6;
  const int lg = l >> 4, lr = l & 15;
  const int wm = w >> 2, wn = w & 3;

  const int nwg = NT * 32;
  const int cpx = nwg >> 3;
  const int bid = blockIdx.x;
  const int swz = (bid & 7) * cpx + (bid >> 3);
  const int by = swz / NT, bx = swz % NT;
  const int rowBase = by * 256, colBase = bx * 256;

  const int rloc = w * 8 + (l >> 3);
  const int cgo  = ((l & 7) ^ (l >> 3)) * 8;
  const u16* gp[8];
#pragma unroll
  for (int seg = 0; seg < 8; seg++) {
    int half = (seg >> 1) & 1;
    int row  = (seg & 1) * 64 + rloc;
    if (seg < 4) gp[seg] = A  + (long)(rowBase + half * 128 + row) * K + cgo;
    else         gp[seg] = Bm + (long)(colBase + half * 128 + row) * K + cgo;
  }

  f32x4 acc[8][4] = {};

  const int NKT = K >> 6;
  {
    char* nb = (char*)&lds[0][0];
#pragma unroll
    for (int seg = 0; seg < 8; seg++)
      GLOAD16(gp[seg], nb + seg * 8192 + w * 1024);
#pragma unroll
    for (int seg = 0; seg < 8; seg++) gp[seg] += 64;
    asm volatile("s_waitcnt vmcnt(0)" ::: "memory");
    __builtin_amdgcn_s_barrier();
    asm volatile("" ::: "memory");
  }

  for (int kt = 0; kt < NKT; kt++) {
    const int cur = kt & 1;
    const bool pre = (kt + 1 < NKT);
    const char* ab = (const char*)&lds[cur][0] + wm * 16384;
    const char* bb = (const char*)&lds[cur][0] + 32768 + (wn >> 1) * 16384;
    char* nb = (char*)&lds[cur ^ 1][0];
    const int rbB = (wn & 1) * 64;

    s16x8 bfr[4][2];
#pragma unroll
    for (int n = 0; n < 4; n++)
#pragma unroll
      for (int ks = 0; ks < 2; ks++) {
        int rb = rbB + n * 16 + lr;
        int c = ks * 4 + lg;
        bfr[n][ks] = *(const s16x8*)(bb + rb * 128 + ((c ^ (rb & 7)) * 16));
      }
    GPHASE(0,
      { if (pre) { GLOAD16(gp[4], nb + 4 * 8192 + w * 1024);
                   GLOAD16(gp[5], nb + 5 * 8192 + w * 1024); } },
      { });
    GPHASE(1,
      { if (pre) { GLOAD16(gp[6], nb + 6 * 8192 + w * 1024);
                   GLOAD16(gp[7], nb + 7 * 8192 + w * 1024); } },
      { if (pre) { asm volatile("s_waitcnt vmcnt(4)" ::: "memory"); }
        else     { asm volatile("s_waitcnt vmcnt(0)" ::: "memory"); } });
    GPHASE(2,
      { if (pre) { GLOAD16(gp[0], nb + 0 * 8192 + w * 1024);
                   GLOAD16(gp[2], nb + 2 * 8192 + w * 1024); } },
      { });
    GPHASE(3,
      { if (pre) { GLOAD16(gp[1], nb + 1 * 8192 + w * 1024);
                   GLOAD16(gp[3], nb + 3 * 8192 + w * 1024); } },
      { if (pre) { asm volatile("s_waitcnt vmcnt(2)" ::: "memory"); } });

    if (pre) {
#pragma unroll
      for (int seg = 0; seg < 8; seg++) gp[seg] += 64;
    }
  }

#pragma unroll
  for (int m = 0; m < 8; m++)
#pragma unroll
    for (int n = 0; n < 4; n++)
#pragma unroll
      for (int r = 0; r < 4; r++)
        epi_store(EPI, rowBase + wm * 128 + m * 16 + lg * 4 + r,
                  colBase + wn * 64 + n * 16 + lr, acc[m][n][r], Oq, Ok, Ov, Of);
}

// ---------------------------------------------------------------- RoPE in-place on Qr, Kr
__global__ void rope_kernel(u16* __restrict__ Qr, u16* __restrict__ Kr)
{
  long gid = (long)blockIdx.x * 256 + threadIdx.x;
  int i = (int)(gid & 63);
  long row = gid >> 6;
  int s;
  u16* p;
  const long qrows = (long)NB * NH * SS;
  if (row < qrows) { s = (int)(row & 2047); p = Qr + row * HD; }
  else             { long r2 = row - qrows; s = (int)(r2 & 2047); p = Kr + r2 * HD; }
  float inv = exp2f(-(float)i * 0.20762050593046015f);   // log2(10000)/64
  float fr = (float)s * inv;
  float c = cosf(fr), sn = sinf(fr);
  float x1 = bf2f(p[i]), x2 = bf2f(p[i + 64]);
  p[i]      = f2bf(x1 * c + x2 * sn);
  p[i + 64] = f2bf(-x1 * sn + x2 * c);
}

// ---------------------------------------------------------------- flash attention (causal, GQA)
// R15 structure + kept from R16: K 16-slot XOR swizzle (conflicts halved),
// exp2-domain softmax. REVERTED: cvt_pk asm -> scalar packbf (m240: inline-asm
// cvt_pk is -37%, blocks compiler scheduling).
__global__ __launch_bounds__(512) void attn_fwd(const u16* __restrict__ Qr, const u16* __restrict__ Kr,
                                                const u16* __restrict__ Vt, u16* __restrict__ Y)
{
  __shared__ __align__(16) u16 Ks[2][64 * 128];   // [kv][d]  256B rows, 16KB each
  __shared__ __align__(16) u16 Vs[2][128 * 64];   // [d][kv]  128B rows, 16KB each

  const int tid = threadIdx.x, l = tid & 63, w = tid >> 6;
  const int lq = l & 31, hi = l >> 5;
  const int p = blockIdx.x, h = blockIdx.y, b = blockIdx.z;
  const int kvh = h >> 2;

  const u16* Kh = Kr + ((long)(b * NKV + kvh)) * SS * HD;
  const u16* Vh = Vt + ((long)(b * NKV + kvh)) * HD * SS;
  const float scale2 = 0.12751744f;                // (1/sqrt(128)) * log2(e)

  auto stageK = [&](int buf, int kvb) {
    char* kb = (char*)&Ks[buf][0];
#pragma unroll
    for (int i = 0; i < 2; i++) {
      int L = w * 2048 + i * 1024 + l * 16;
      int r = L >> 8;                              // kv row 0..63
      int cl = (L >> 4) & 15;                      // stored chunk slot
      int cg = (cl ^ r) & 15;                      // 16-slot swizzle
      GLOAD16((const char*)(Kh + (long)(kvb + r) * HD) + cg * 16, kb + w * 2048 + i * 1024);
    }
  };
  auto stageV = [&](int buf, int kvb) {
    char* vb = (char*)&Vs[buf][0];
#pragma unroll
    for (int i = 0; i < 2; i++) {
      int L = w * 2048 + i * 1024 + l * 16;
      int r = L >> 7;                              // d row 0..127
      int cl = (L >> 4) & 7;
      int cg = (cl ^ r) & 7;
      GLOAD16((const char*)(Vh + (long)r * SS + kvb) + cg * 16, vb + w * 2048 + i * 1024);
    }
  };

  for (int job = 0; job < 2; job++) {
    const int qt = job ? p : 7 - p;                // big job first
    const int qRow0 = qt * 256 + w * 32;
    const int qMax = qRow0 + 31;
    const int nT = 4 * qt + 4;
    const int myq = qRow0 + lq;
    const u16* Qh = Qr + (((long)(b * NH + h)) * SS + qRow0) * HD;
    u16* Yh = Y + ((long)b * SS) * DMODEL + h * HD;

    s16x8 qf[8];
#pragma unroll
    for (int kk = 0; kk < 8; kk++)
      qf[kk] = *(const s16x8*)(Qh + (long)lq * HD + kk * 16 + hi * 8);

    float m_run = -1e30f, l_run = 0.f;             // m in log2 domain
    f32x16 oacc[4] = {};                           // row=crow(r,hi)=q, col=lane&31=d

    stageK(0, 0); stageV(0, 0);

    for (int t = 0; t < nT; t++) {
      const int cur = t & 1;
      if (t + 1 < nT) {
        stageK(cur ^ 1, (t + 1) * 64);
        stageV(cur ^ 1, (t + 1) * 64);
        asm volatile("s_waitcnt vmcnt(4)" ::: "memory");
      } else {
        asm volatile("s_waitcnt vmcnt(0)" ::: "memory");
      }
      __builtin_amdgcn_s_barrier();
      asm volatile("" ::: "memory");

      if (t * 64 <= qMax) {
        const char* kb = (const char*)&Ks[cur][0];
        const char* vb = (const char*)&Vs[cur][0];
        f32x16 sacc[2] = {};
#pragma unroll
        for (int kk = 0; kk < 8; kk++) {
          int ch = kk * 2 + hi;
#pragma unroll
          for (int tile = 0; tile < 2; tile++) {
            int rr = tile * 32 + lq;
            int cs = (ch ^ rr) & 15;               // 16-slot swizzle
            s16x8 kf = *(const s16x8*)(kb + rr * 256 + cs * 16);
            sacc[tile] = __builtin_amdgcn_mfma_f32_32x32x16_bf16(kf, qf[kk], sacc[tile], 0, 0, 0);
          }
        }
        const bool full = (t * 64 + 63 <= qRow0);
        float pmax = -1e30f;
#pragma unroll
        for (int tile = 0; tile < 2; tile++)
#pragma unroll
          for (int r = 0; r < 16; r++) {
            int kv = t * 64 + tile * 32 + (r & 3) + 8 * (r >> 2) + 4 * hi;
            float v = sacc[tile][r] * scale2;      // log2-scaled scores
            if (!full && kv > myq) v = -30000.f;
            sacc[tile][r] = v;
            pmax = fmaxf(pmax, v);
          }
        pmax = fmaxf(pmax, __shfl_xor(pmax, 32));
        if (!__all(pmax - m_run <= 11.54f)) {      // defer-max (8 nats in log2)
          float mnew = fmaxf(m_run, pmax);
          float sf = exp2f(m_run - mnew);
          m_run = mnew; l_run *= sf;
          int sfi = __builtin_bit_cast(int, sf);
#pragma unroll
          for (int r = 0; r < 16; r++) {
            int qq = (r & 3) + 8 * (r >> 2) + 4 * hi;
            float sfr = __builtin_bit_cast(float, __builtin_amdgcn_ds_bpermute(qq << 2, sfi));
#pragma unroll
            for (int n = 0; n < 4; n++) oacc[n][r] *= sfr;
          }
        }
        float rs = 0.f;
#pragma unroll
        for (int tile = 0; tile < 2; tile++)
#pragma unroll
          for (int r = 0; r < 16; r++) {
            float pv = exp2f(sacc[tile][r] - m_run);   // bare v_exp_f32
            sacc[tile][r] = pv;
            rs += pv;
          }
        rs += __shfl_xor(rs, 32);
        l_run += rs;
        s16x8 pav[4];
#pragma unroll
        for (int tile = 0; tile < 2; tile++) {
          u32 qk[8], sw[8];
#pragma unroll
          for (int j = 0; j < 8; j++) {
            qk[j] = packbf(sacc[tile][2 * j], sacc[tile][2 * j + 1]);
            sw[j] = __shfl_xor(qk[j], 32);
          }
          u32x4 f0, f1;
          f0[0] = hi ? sw[2] : qk[0];
          f0[1] = hi ? sw[3] : qk[1];
          f0[2] = hi ? qk[2] : sw[0];
          f0[3] = hi ? qk[3] : sw[1];
          f1[0] = hi ? sw[6] : qk[4];
          f1[1] = hi ? sw[7] : qk[5];
          f1[2] = hi ? qk[6] : sw[4];
          f1[3] = hi ? qk[7] : sw[5];
          pav[tile * 2 + 0] = __builtin_bit_cast(s16x8, f0);
          pav[tile * 2 + 1] = __builtin_bit_cast(s16x8, f1);
        }
#pragma unroll
        for (int n = 0; n < 4; n++) {
          int rr = n * 32 + lq;
#pragma unroll
          for (int kk = 0; kk < 4; kk++) {
            int ch = kk * 2 + hi;
            int cs = (ch ^ rr) & 7;
            s16x8 vf = *(const s16x8*)(vb + rr * 128 + cs * 16);
            oacc[n] = __builtin_amdgcn_mfma_f32_32x32x16_bf16(pav[kk], vf, oacc[n], 0, 0, 0);
          }
        }
      }
      asm volatile("" ::: "memory");
      __builtin_amdgcn_s_barrier();
      asm volatile("" ::: "memory");
    }

    float linv = 1.f / l_run;
    int li = __builtin_bit_cast(int, linv);
#pragma unroll
    for (int r = 0; r < 16; r++) {
      int qq = (r & 3) + 8 * (r >> 2) + 4 * hi;
      float lr_ = __builtin_bit_cast(float, __builtin_amdgcn_ds_bpermute(qq << 2, li));
      u16* yrow = Yh + (long)(qRow0 + qq) * DMODEL;
#pragma unroll
      for (int n = 0; n < 4; n++)
        yrow[n * 32 + lq] = f2bf(oacc[n][r] * lr_);
    }
  }
}

// ---------------------------------------------------------------- launch
extern "C" void kernel_launch(void* const* d_in, const int* in_sizes, int n_in,
                              void* d_out, int out_size, void* d_ws, size_t ws_size,
                              hipStream_t stream) {
  const float* x  = (const float*)d_in[0];
  const float* wq = (const float*)d_in[1];
  const float* wk = (const float*)d_in[2];
  const float* wv = (const float*)d_in[3];
  const float* wo = (const float*)d_in[4];
  float* out = (float*)d_out;
  char* ws = (char*)d_ws;

  u16* Xb   = (u16*)ws;                    // 33,554,432 B  (aliased as Y after qkv gemms)
  u16* Wqkv = (u16*)(ws + 33554432);       // 12,582,912 B
  u16* Wob  = (u16*)(ws + 46137344);       //  8,388,608 B
  u16* Qr   = (u16*)(ws + 54525952);       // 33,554,432 B
  u16* Kr   = (u16*)(ws + 88080384);       //  8,388,608 B
  u16* Vt   = (u16*)(ws + 96468992);       //  8,388,608 B
  u16* Y    = Xb;

  cast_all<<<26624, 256, 0, stream>>>(x, wq, wk, wv, wo, Xb, Wqkv, Wob);
  gemm256<8, 0><<<256, 512, 0, stream>>>(Xb, Wqkv, DMODEL, Qr, Kr, Vt, nullptr);
  gemm128<4, 2048><<<256, 512, 0, stream>>>(Xb, Wqkv + 2048 * 2048, DMODEL, Qr, Kr, Vt);
  rope_kernel<<<40960, 256, 0, stream>>>(Qr, Kr);
  dim3 ag(4, NH, NB);
  attn_fwd<<<ag, 512, 0, stream>>>(Qr, Kr, Vt, Y);
  gemm256<8, 1><<<256, 512, 0, stream>>>(Y, Wob, DMODEL, nullptr, nullptr, nullptr, out);
}

// Round 18
// 357.426 us; speedup vs baseline: 1.0241x; 1.0241x over previous
//
#include <hip/hip_runtime.h>
#include <hip/hip_bf16.h>

typedef short s16x8 __attribute__((ext_vector_type(8)));
typedef float f32x4 __attribute__((ext_vector_type(4)));
typedef float f32x16 __attribute__((ext_vector_type(16)));
typedef unsigned u32;
typedef unsigned u32x4 __attribute__((ext_vector_type(4)));
typedef unsigned short u16;

#define DMODEL 2048
#define NH     16
#define NKV    4
#define HD     128
#define NB     4
#define SS     2048

static __device__ __forceinline__ u16 f2bf(float f) {
  unsigned u = __builtin_bit_cast(unsigned, f);
  u += 0x7fffu + ((u >> 16) & 1u);          // RNE
  return (u16)(u >> 16);
}
static __device__ __forceinline__ float bf2f(u16 h) {
  unsigned u = ((unsigned)h) << 16;
  return __builtin_bit_cast(float, u);
}
static __device__ __forceinline__ u32 cvtpk(float a, float b) {   // a -> lo, b -> hi
  u32 r;
  asm("v_cvt_pk_bf16_f32 %0, %1, %2" : "=v"(r) : "v"(a), "v"(b));
  return r;
}

typedef const __attribute__((address_space(1))) void* gas_p;
typedef __attribute__((address_space(3))) void* las_p;
#define GLOAD16(g, l) __builtin_amdgcn_global_load_lds((gas_p)(const void*)(g), (las_p)(void*)(l), 16, 0, 0)

// ---------------------------------------------------------------- cast: f32 -> bf16
__global__ void cast_all(const float* __restrict__ x,  const float* __restrict__ wq,
                         const float* __restrict__ wk, const float* __restrict__ wv,
                         const float* __restrict__ wo,
                         u16* __restrict__ xb, u16* __restrict__ wqkv, u16* __restrict__ wob)
{
  long gid = (long)blockIdx.x * 256 + threadIdx.x;
  long i = gid * 4;
  const float* src; u16* dst; long off;
  if (i < 16777216L)       { src = x;  dst = xb;             off = i; }
  else if (i < 20971520L)  { src = wq; dst = wqkv;           off = i - 16777216L; }
  else if (i < 22020096L)  { src = wk; dst = wqkv + 4194304; off = i - 20971520L; }
  else if (i < 23068672L)  { src = wv; dst = wqkv + 5242880; off = i - 22020096L; }
  else                     { src = wo; dst = wob;            off = i - 23068672L; }
  float4 v = *(const float4*)(src + off);
  ushort4 o;
  o.x = f2bf(v.x); o.y = f2bf(v.y); o.z = f2bf(v.z); o.w = f2bf(v.w);
  *(ushort4*)(dst + off) = o;
}

// ---------------------------------------------------------------- epilogue scatter (shared)
static __device__ __forceinline__ void epi_store(int EPI, int row, int col, float v,
    u16* __restrict__ Oq, u16* __restrict__ Ok, u16* __restrict__ Ov, float* __restrict__ Of)
{
  if (EPI == 0) {
    int b = row >> 11, s = row & 2047;
    u16 hv = f2bf(v);
    if (col < 2048) {
      int hh = col >> 7, d = col & 127;
      Oq[(((long)(b * NH + hh)) * SS + s) * HD + d] = hv;
    } else if (col < 2560) {
      int c2 = col - 2048, kh = c2 >> 7, d = c2 & 127;
      Ok[(((long)(b * NKV + kh)) * SS + s) * HD + d] = hv;
    } else {
      int c2 = col - 2560, kh = c2 >> 7, d = c2 & 127;
      Ov[(((long)(b * NKV + kh)) * HD + d) * SS + s] = hv;   // V transposed [d][s]
    }
  } else {
    Of[(long)row * DMODEL + col] = v;
  }
}

// ---------------------------------------------------------------- GEMM 128x256 (KV) — R10-verified, + col offset
template<int NTC, int COFF>
__global__ __launch_bounds__(512) void gemm128(
    const u16* __restrict__ A, const u16* __restrict__ Bm, int K,
    u16* __restrict__ Oq, u16* __restrict__ Ok, u16* __restrict__ Ov)
{
  __shared__ __align__(16) u16 lds[2][24576];     // 48KB each
  const int tid = threadIdx.x, l = tid & 63, w = tid >> 6;
  const int lg = l >> 4, lr = l & 15;
  const int wm = w >> 2, wn = w & 3;

  const int nwg = NTC * 64;
  const int cpx = nwg >> 3;
  const int bid = blockIdx.x;
  const int swz = (bid & 7) * cpx + (bid >> 3);   // bijective: nwg % 8 == 0
  const int by = swz / NTC, bx = swz % NTC;
  const int rowBase = by * 128, colBase = bx * 256;

  const int rloc = w * 8 + (l >> 3);
  const int cgo  = ((l & 7) ^ (l >> 3)) * 8;
  const u16* gp[6];
#pragma unroll
  for (int seg = 0; seg < 6; seg++) {
    if (seg < 2) gp[seg] = A  + (long)(rowBase + seg * 64 + rloc) * K + cgo;
    else         gp[seg] = Bm + (long)(colBase + (seg - 2) * 64 + rloc) * K + cgo;
  }

  f32x4 acc[4][4] = {};

  auto stage = [&](int buf) {
    char* base = (char*)&lds[buf][0];
#pragma unroll
    for (int seg = 0; seg < 6; seg++)
      GLOAD16(gp[seg], base + seg * 8192 + w * 1024);
  };

  const int NKT = K >> 6;
  stage(0);
#pragma unroll
  for (int seg = 0; seg < 6; seg++) gp[seg] += 64;
  asm volatile("s_waitcnt vmcnt(0)" ::: "memory");
  __builtin_amdgcn_s_barrier();

  for (int kt = 0; kt < NKT; kt++) {
    const int cur = kt & 1;
    if (kt + 1 < NKT) {
      stage(cur ^ 1);
#pragma unroll
      for (int seg = 0; seg < 6; seg++) gp[seg] += 64;
      asm volatile("s_waitcnt vmcnt(6)" ::: "memory");
    } else {
      asm volatile("s_waitcnt vmcnt(0)" ::: "memory");
    }
    __builtin_amdgcn_s_barrier();
    asm volatile("" ::: "memory");

    const char* ab = (const char*)&lds[cur][0] + wm * 8192;
    const char* bb = (const char*)&lds[cur][0] + (2 + wn) * 8192;
    s16x8 af[4][2], bfr[4][2];
#pragma unroll
    for (int m = 0; m < 4; m++)
#pragma unroll
      for (int ks = 0; ks < 2; ks++) {
        int rr = m * 16 + lr;
        int c = ks * 4 + lg;
        af[m][ks]  = *(const s16x8*)(ab + rr * 128 + ((c ^ (rr & 7)) * 16));
        bfr[m][ks] = *(const s16x8*)(bb + rr * 128 + ((c ^ (rr & 7)) * 16));
      }
    __builtin_amdgcn_s_setprio(1);
#pragma unroll
    for (int ks = 0; ks < 2; ks++)
#pragma unroll
      for (int m = 0; m < 4; m++)
#pragma unroll
        for (int n = 0; n < 4; n++)
          acc[m][n] = __builtin_amdgcn_mfma_f32_16x16x32_bf16(af[m][ks], bfr[n][ks], acc[m][n], 0, 0, 0);
    __builtin_amdgcn_s_setprio(0);
    asm volatile("" ::: "memory");
    __builtin_amdgcn_s_barrier();
    asm volatile("" ::: "memory");
  }

#pragma unroll
  for (int m = 0; m < 4; m++)
#pragma unroll
    for (int n = 0; n < 4; n++)
#pragma unroll
      for (int r = 0; r < 4; r++)
        epi_store(0, rowBase + wm * 64 + m * 16 + lg * 4 + r,
                  COFF + colBase + wn * 64 + n * 16 + lr, acc[m][n][r], Oq, Ok, Ov, nullptr);
}

// ---------------------------------------------------------------- GEMM 256x256 — R9 4-phase, unchanged
#define GPHASE(MQ, STG, WAIT)                                               \
  {                                                                         \
    s16x8 af[2][2];                                                         \
    _Pragma("unroll") for (int j = 0; j < 2; j++)                           \
      _Pragma("unroll") for (int ks = 0; ks < 2; ks++) {                    \
        int rr = (MQ) * 32 + j * 16 + lr;                                   \
        int c = ks * 4 + lg;                                                \
        af[j][ks] = *(const s16x8*)(ab + rr * 128 + ((c ^ (rr & 7)) * 16)); \
      }                                                                     \
    STG;                                                                    \
    WAIT;                                                                   \
    asm volatile("" ::: "memory");                                          \
    __builtin_amdgcn_s_barrier();                                           \
    asm volatile("" ::: "memory");                                          \
    __builtin_amdgcn_s_setprio(1);                                          \
    _Pragma("unroll") for (int ks = 0; ks < 2; ks++)                        \
      _Pragma("unroll") for (int j = 0; j < 2; j++)                         \
        _Pragma("unroll") for (int n = 0; n < 4; n++)                       \
          acc[(MQ) * 2 + j][n] = __builtin_amdgcn_mfma_f32_16x16x32_bf16(   \
              af[j][ks], bfr[n][ks], acc[(MQ) * 2 + j][n], 0, 0, 0);        \
    __builtin_amdgcn_s_setprio(0);                                          \
    asm volatile("" ::: "memory");                                          \
    __builtin_amdgcn_s_barrier();                                           \
    asm volatile("" ::: "memory");                                          \
  }

template<int NT, int EPI>
__global__ __launch_bounds__(512) void gemm256(
    const u16* __restrict__ A, const u16* __restrict__ Bm, int K,
    u16* __restrict__ Oq, u16* __restrict__ Ok, u16* __restrict__ Ov, float* __restrict__ Of)
{
  __shared__ __align__(16) u16 lds[2][32768];     // 2 x 64KB
  const int tid = threadIdx.x, l = tid & 63, w = tid >> 6;
  const int lg = l >> 4, lr = l & 15;
  const int wm = w >> 2, wn = w & 3;

  const int nwg = NT * 32;
  const int cpx = nwg >> 3;
  const int bid = blockIdx.x;
  const int swz = (bid & 7) * cpx + (bid >> 3);
  const int by = swz / NT, bx = swz % NT;
  const int rowBase = by * 256, colBase = bx * 256;

  const int rloc = w * 8 + (l >> 3);
  const int cgo  = ((l & 7) ^ (l >> 3)) * 8;
  const u16* gp[8];
#pragma unroll
  for (int seg = 0; seg < 8; seg++) {
    int half = (seg >> 1) & 1;
    int row  = (seg & 1) * 64 + rloc;
    if (seg < 4) gp[seg] = A  + (long)(rowBase + half * 128 + row) * K + cgo;
    else         gp[seg] = Bm + (long)(colBase + half * 128 + row) * K + cgo;
  }

  f32x4 acc[8][4] = {};

  const int NKT = K >> 6;
  {
    char* nb = (char*)&lds[0][0];
#pragma unroll
    for (int seg = 0; seg < 8; seg++)
      GLOAD16(gp[seg], nb + seg * 8192 + w * 1024);
#pragma unroll
    for (int seg = 0; seg < 8; seg++) gp[seg] += 64;
    asm volatile("s_waitcnt vmcnt(0)" ::: "memory");
    __builtin_amdgcn_s_barrier();
    asm volatile("" ::: "memory");
  }

  for (int kt = 0; kt < NKT; kt++) {
    const int cur = kt & 1;
    const bool pre = (kt + 1 < NKT);
    const char* ab = (const char*)&lds[cur][0] + wm * 16384;
    const char* bb = (const char*)&lds[cur][0] + 32768 + (wn >> 1) * 16384;
    char* nb = (char*)&lds[cur ^ 1][0];
    const int rbB = (wn & 1) * 64;

    s16x8 bfr[4][2];
#pragma unroll
    for (int n = 0; n < 4; n++)
#pragma unroll
      for (int ks = 0; ks < 2; ks++) {
        int rb = rbB + n * 16 + lr;
        int c = ks * 4 + lg;
        bfr[n][ks] = *(const s16x8*)(bb + rb * 128 + ((c ^ (rb & 7)) * 16));
      }
    GPHASE(0,
      { if (pre) { GLOAD16(gp[4], nb + 4 * 8192 + w * 1024);
                   GLOAD16(gp[5], nb + 5 * 8192 + w * 1024); } },
      { });
    GPHASE(1,
      { if (pre) { GLOAD16(gp[6], nb + 6 * 8192 + w * 1024);
                   GLOAD16(gp[7], nb + 7 * 8192 + w * 1024); } },
      { if (pre) { asm volatile("s_waitcnt vmcnt(4)" ::: "memory"); }
        else     { asm volatile("s_waitcnt vmcnt(0)" ::: "memory"); } });
    GPHASE(2,
      { if (pre) { GLOAD16(gp[0], nb + 0 * 8192 + w * 1024);
                   GLOAD16(gp[2], nb + 2 * 8192 + w * 1024); } },
      { });
    GPHASE(3,
      { if (pre) { GLOAD16(gp[1], nb + 1 * 8192 + w * 1024);
                   GLOAD16(gp[3], nb + 3 * 8192 + w * 1024); } },
      { if (pre) { asm volatile("s_waitcnt vmcnt(2)" ::: "memory"); } });

    if (pre) {
#pragma unroll
      for (int seg = 0; seg < 8; seg++) gp[seg] += 64;
    }
  }

#pragma unroll
  for (int m = 0; m < 8; m++)
#pragma unroll
    for (int n = 0; n < 4; n++)
#pragma unroll
      for (int r = 0; r < 4; r++)
        epi_store(EPI, rowBase + wm * 128 + m * 16 + lg * 4 + r,
                  colBase + wn * 64 + n * 16 + lr, acc[m][n][r], Oq, Ok, Ov, Of);
}

// ---------------------------------------------------------------- RoPE in-place on Qr, Kr
__global__ void rope_kernel(u16* __restrict__ Qr, u16* __restrict__ Kr)
{
  long gid = (long)blockIdx.x * 256 + threadIdx.x;
  int i = (int)(gid & 63);
  long row = gid >> 6;
  int s;
  u16* p;
  const long qrows = (long)NB * NH * SS;
  if (row < qrows) { s = (int)(row & 2047); p = Qr + row * HD; }
  else             { long r2 = row - qrows; s = (int)(r2 & 2047); p = Kr + r2 * HD; }
  float inv = exp2f(-(float)i * 0.20762050593046015f);   // log2(10000)/64
  float fr = (float)s * inv;
  float c = cosf(fr), sn = sinf(fr);
  float x1 = bf2f(p[i]), x2 = bf2f(p[i + 64]);
  p[i]      = f2bf(x1 * c + x2 * sn);
  p[i + 64] = f2bf(-x1 * sn + x2 * c);
}

// ---------------------------------------------------------------- flash attention (causal, GQA)
// R15-proven structure (8-slot K swizzle, __expf softmax, THR=8) with ONE change:
// P pack via v_cvt_pk_bf16_f32 (R16 vs R17 isolated: cvtpk beats scalar pack by
// ~9us in this VALU-bound kernel).
__global__ __launch_bounds__(512) void attn_fwd(const u16* __restrict__ Qr, const u16* __restrict__ Kr,
                                                const u16* __restrict__ Vt, u16* __restrict__ Y)
{
  __shared__ __align__(16) u16 Ks[2][64 * 128];   // [kv][d]  256B rows, 16KB each
  __shared__ __align__(16) u16 Vs[2][128 * 64];   // [d][kv]  128B rows, 16KB each

  const int tid = threadIdx.x, l = tid & 63, w = tid >> 6;
  const int lq = l & 31, hi = l >> 5;
  const int p = blockIdx.x, h = blockIdx.y, b = blockIdx.z;
  const int kvh = h >> 2;

  const u16* Kh = Kr + ((long)(b * NKV + kvh)) * SS * HD;
  const u16* Vh = Vt + ((long)(b * NKV + kvh)) * HD * SS;
  const float scale = 0.08838834764831845f;        // 1/sqrt(128)

  auto stageK = [&](int buf, int kvb) {
    char* kb = (char*)&Ks[buf][0];
#pragma unroll
    for (int i = 0; i < 2; i++) {
      int L = w * 2048 + i * 1024 + l * 16;
      int r = L >> 8;                              // kv row 0..63
      int cl = (L >> 4) & 15;
      int cg = (cl & 8) | ((cl ^ r) & 7);          // 8-slot swizzle (R15)
      GLOAD16((const char*)(Kh + (long)(kvb + r) * HD) + cg * 16, kb + w * 2048 + i * 1024);
    }
  };
  auto stageV = [&](int buf, int kvb) {
    char* vb = (char*)&Vs[buf][0];
#pragma unroll
    for (int i = 0; i < 2; i++) {
      int L = w * 2048 + i * 1024 + l * 16;
      int r = L >> 7;                              // d row 0..127
      int cl = (L >> 4) & 7;
      int cg = (cl ^ r) & 7;
      GLOAD16((const char*)(Vh + (long)r * SS + kvb) + cg * 16, vb + w * 2048 + i * 1024);
    }
  };

  for (int job = 0; job < 2; job++) {
    const int qt = job ? p : 7 - p;                // big job first
    const int qRow0 = qt * 256 + w * 32;
    const int qMax = qRow0 + 31;
    const int nT = 4 * qt + 4;
    const int myq = qRow0 + lq;
    const u16* Qh = Qr + (((long)(b * NH + h)) * SS + qRow0) * HD;
    u16* Yh = Y + ((long)b * SS) * DMODEL + h * HD;

    s16x8 qf[8];
#pragma unroll
    for (int kk = 0; kk < 8; kk++)
      qf[kk] = *(const s16x8*)(Qh + (long)lq * HD + kk * 16 + hi * 8);

    float m_run = -1e30f, l_run = 0.f;
    f32x16 oacc[4] = {};                           // row=crow(r,hi)=q, col=lane&31=d

    stageK(0, 0); stageV(0, 0);

    for (int t = 0; t < nT; t++) {
      const int cur = t & 1;
      if (t + 1 < nT) {
        stageK(cur ^ 1, (t + 1) * 64);
        stageV(cur ^ 1, (t + 1) * 64);
        asm volatile("s_waitcnt vmcnt(4)" ::: "memory");
      } else {
        asm volatile("s_waitcnt vmcnt(0)" ::: "memory");
      }
      __builtin_amdgcn_s_barrier();
      asm volatile("" ::: "memory");

      if (t * 64 <= qMax) {
        const char* kb = (const char*)&Ks[cur][0];
        const char* vb = (const char*)&Vs[cur][0];
        f32x16 sacc[2] = {};
#pragma unroll
        for (int kk = 0; kk < 8; kk++) {
          int ch = kk * 2 + hi;
#pragma unroll
          for (int tile = 0; tile < 2; tile++) {
            int rr = tile * 32 + lq;
            int cs = (ch & 8) | ((ch ^ rr) & 7);   // 8-slot swizzle (R15)
            s16x8 kf = *(const s16x8*)(kb + rr * 256 + cs * 16);
            sacc[tile] = __builtin_amdgcn_mfma_f32_32x32x16_bf16(kf, qf[kk], sacc[tile], 0, 0, 0);
          }
        }
        const bool full = (t * 64 + 63 <= qRow0);
        float pmax = -1e30f;
#pragma unroll
        for (int tile = 0; tile < 2; tile++)
#pragma unroll
          for (int r = 0; r < 16; r++) {
            int kv = t * 64 + tile * 32 + (r & 3) + 8 * (r >> 2) + 4 * hi;
            float v = sacc[tile][r] * scale;
            if (!full && kv > myq) v = -30000.f;
            sacc[tile][r] = v;
            pmax = fmaxf(pmax, v);
          }
        pmax = fmaxf(pmax, __shfl_xor(pmax, 32));
        if (!__all(pmax - m_run <= 8.0f)) {
          float mnew = fmaxf(m_run, pmax);
          float sf = __expf(m_run - mnew);
          m_run = mnew; l_run *= sf;
          int sfi = __builtin_bit_cast(int, sf);
#pragma unroll
          for (int r = 0; r < 16; r++) {
            int qq = (r & 3) + 8 * (r >> 2) + 4 * hi;
            float sfr = __builtin_bit_cast(float, __builtin_amdgcn_ds_bpermute(qq << 2, sfi));
#pragma unroll
            for (int n = 0; n < 4; n++) oacc[n][r] *= sfr;
          }
        }
        float rs = 0.f;
#pragma unroll
        for (int tile = 0; tile < 2; tile++)
#pragma unroll
          for (int r = 0; r < 16; r++) {
            float pv = __expf(sacc[tile][r] - m_run);
            sacc[tile][r] = pv;
            rs += pv;
          }
        rs += __shfl_xor(rs, 32);
        l_run += rs;
        s16x8 pav[4];
#pragma unroll
        for (int tile = 0; tile < 2; tile++) {
          u32 qk[8], sw[8];
#pragma unroll
          for (int j = 0; j < 8; j++) {
            qk[j] = cvtpk(sacc[tile][2 * j], sacc[tile][2 * j + 1]);
            sw[j] = __shfl_xor(qk[j], 32);
          }
          u32x4 f0, f1;
          f0[0] = hi ? sw[2] : qk[0];
          f0[1] = hi ? sw[3] : qk[1];
          f0[2] = hi ? qk[2] : sw[0];
          f0[3] = hi ? qk[3] : sw[1];
          f1[0] = hi ? sw[6] : qk[4];
          f1[1] = hi ? sw[7] : qk[5];
          f1[2] = hi ? qk[6] : sw[4];
          f1[3] = hi ? qk[7] : sw[5];
          pav[tile * 2 + 0] = __builtin_bit_cast(s16x8, f0);
          pav[tile * 2 + 1] = __builtin_bit_cast(s16x8, f1);
        }
#pragma unroll
        for (int n = 0; n < 4; n++) {
          int rr = n * 32 + lq;
#pragma unroll
          for (int kk = 0; kk < 4; kk++) {
            int ch = kk * 2 + hi;
            int cs = (ch ^ rr) & 7;
            s16x8 vf = *(const s16x8*)(vb + rr * 128 + cs * 16);
            oacc[n] = __builtin_amdgcn_mfma_f32_32x32x16_bf16(pav[kk], vf, oacc[n], 0, 0, 0);
          }
        }
      }
      asm volatile("" ::: "memory");
      __builtin_amdgcn_s_barrier();
      asm volatile("" ::: "memory");
    }

    float linv = 1.f / l_run;
    int li = __builtin_bit_cast(int, linv);
#pragma unroll
    for (int r = 0; r < 16; r++) {
      int qq = (r & 3) + 8 * (r >> 2) + 4 * hi;
      float lr_ = __builtin_bit_cast(float, __builtin_amdgcn_ds_bpermute(qq << 2, li));
      u16* yrow = Yh + (long)(qRow0 + qq) * DMODEL;
#pragma unroll
      for (int n = 0; n < 4; n++)
        yrow[n * 32 + lq] = f2bf(oacc[n][r] * lr_);
    }
  }
}

// ---------------------------------------------------------------- launch
extern "C" void kernel_launch(void* const* d_in, const int* in_sizes, int n_in,
                              void* d_out, int out_size, void* d_ws, size_t ws_size,
                              hipStream_t stream) {
  const float* x  = (const float*)d_in[0];
  const float* wq = (const float*)d_in[1];
  const float* wk = (const float*)d_in[2];
  const float* wv = (const float*)d_in[3];
  const float* wo = (const float*)d_in[4];
  float* out = (float*)d_out;
  char* ws = (char*)d_ws;

  u16* Xb   = (u16*)ws;                    // 33,554,432 B  (aliased as Y after qkv gemms)
  u16* Wqkv = (u16*)(ws + 33554432);       // 12,582,912 B
  u16* Wob  = (u16*)(ws + 46137344);       //  8,388,608 B
  u16* Qr   = (u16*)(ws + 54525952);       // 33,554,432 B
  u16* Kr   = (u16*)(ws + 88080384);       //  8,388,608 B
  u16* Vt   = (u16*)(ws + 96468992);       //  8,388,608 B
  u16* Y    = Xb;

  cast_all<<<26624, 256, 0, stream>>>(x, wq, wk, wv, wo, Xb, Wqkv, Wob);
  gemm256<8, 0><<<256, 512, 0, stream>>>(Xb, Wqkv, DMODEL, Qr, Kr, Vt, nullptr);
  gemm128<4, 2048><<<256, 512, 0, stream>>>(Xb, Wqkv + 2048 * 2048, DMODEL, Qr, Kr, Vt);
  rope_kernel<<<40960, 256, 0, stream>>>(Qr, Kr);
  dim3 ag(4, NH, NB);
  attn_fwd<<<ag, 512, 0, stream>>>(Qr, Kr, Vt, Y);
  gemm256<8, 1><<<256, 512, 0, stream>>>(Y, Wob, DMODEL, nullptr, nullptr, nullptr, out);
}

// Round 19
// 339.015 us; speedup vs baseline: 1.0797x; 1.0543x over previous
//
#include <hip/hip_runtime.h>
#include <hip/hip_bf16.h>

typedef short s16x8 __attribute__((ext_vector_type(8)));
typedef float f32x4 __attribute__((ext_vector_type(4)));
typedef float f32x16 __attribute__((ext_vector_type(16)));
typedef unsigned u32;
typedef unsigned u32x4 __attribute__((ext_vector_type(4)));
typedef unsigned short u16;

#define DMODEL 2048
#define NH     16
#define NKV    4
#define HD     128
#define NB     4
#define SS     2048

static __device__ __forceinline__ u16 f2bf(float f) {
  unsigned u = __builtin_bit_cast(unsigned, f);
  u += 0x7fffu + ((u >> 16) & 1u);          // RNE
  return (u16)(u >> 16);
}
static __device__ __forceinline__ float bf2f(u16 h) {
  unsigned u = ((unsigned)h) << 16;
  return __builtin_bit_cast(float, u);
}
static __device__ __forceinline__ u32 cvtpk(float a, float b) {   // a -> lo, b -> hi
  u32 r;
  asm("v_cvt_pk_bf16_f32 %0, %1, %2" : "=v"(r) : "v"(a), "v"(b));
  return r;
}

typedef const __attribute__((address_space(1))) void* gas_p;
typedef __attribute__((address_space(3))) void* las_p;
#define GLOAD16(g, l) __builtin_amdgcn_global_load_lds((gas_p)(const void*)(g), (las_p)(void*)(l), 16, 0, 0)

// ---------------------------------------------------------------- cast: f32 -> bf16
__global__ void cast_all(const float* __restrict__ x,  const float* __restrict__ wq,
                         const float* __restrict__ wk, const float* __restrict__ wv,
                         const float* __restrict__ wo,
                         u16* __restrict__ xb, u16* __restrict__ wqkv, u16* __restrict__ wob)
{
  long gid = (long)blockIdx.x * 256 + threadIdx.x;
  long i = gid * 4;
  const float* src; u16* dst; long off;
  if (i < 16777216L)       { src = x;  dst = xb;             off = i; }
  else if (i < 20971520L)  { src = wq; dst = wqkv;           off = i - 16777216L; }
  else if (i < 22020096L)  { src = wk; dst = wqkv + 4194304; off = i - 20971520L; }
  else if (i < 23068672L)  { src = wv; dst = wqkv + 5242880; off = i - 22020096L; }
  else                     { src = wo; dst = wob;            off = i - 23068672L; }
  float4 v = *(const float4*)(src + off);
  ushort4 o;
  o.x = f2bf(v.x); o.y = f2bf(v.y); o.z = f2bf(v.z); o.w = f2bf(v.w);
  *(ushort4*)(dst + off) = o;
}

// ---------------------------------------------------------------- epilogue scatter (shared)
// Q gets the softmax scale folded in (commutes with RoPE rotation).
static __device__ __forceinline__ void epi_store(int EPI, int row, int col, float v,
    u16* __restrict__ Oq, u16* __restrict__ Ok, u16* __restrict__ Ov, float* __restrict__ Of)
{
  if (EPI == 0) {
    int b = row >> 11, s = row & 2047;
    if (col < 2048) {
      int hh = col >> 7, d = col & 127;
      Oq[(((long)(b * NH + hh)) * SS + s) * HD + d] = f2bf(v * 0.08838834764831845f);
    } else if (col < 2560) {
      int c2 = col - 2048, kh = c2 >> 7, d = c2 & 127;
      Ok[(((long)(b * NKV + kh)) * SS + s) * HD + d] = f2bf(v);
    } else {
      int c2 = col - 2560, kh = c2 >> 7, d = c2 & 127;
      Ov[(((long)(b * NKV + kh)) * HD + d) * SS + s] = f2bf(v);   // V transposed [d][s]
    }
  } else {
    Of[(long)row * DMODEL + col] = v;
  }
}

// ---------------------------------------------------------------- GEMM 128x256 (KV) — R10-verified, + col offset
template<int NTC, int COFF>
__global__ __launch_bounds__(512) void gemm128(
    const u16* __restrict__ A, const u16* __restrict__ Bm, int K,
    u16* __restrict__ Oq, u16* __restrict__ Ok, u16* __restrict__ Ov)
{
  __shared__ __align__(16) u16 lds[2][24576];     // 48KB each
  const int tid = threadIdx.x, l = tid & 63, w = tid >> 6;
  const int lg = l >> 4, lr = l & 15;
  const int wm = w >> 2, wn = w & 3;

  const int nwg = NTC * 64;
  const int cpx = nwg >> 3;
  const int bid = blockIdx.x;
  const int swz = (bid & 7) * cpx + (bid >> 3);   // bijective: nwg % 8 == 0
  const int by = swz / NTC, bx = swz % NTC;
  const int rowBase = by * 128, colBase = bx * 256;

  const int rloc = w * 8 + (l >> 3);
  const int cgo  = ((l & 7) ^ (l >> 3)) * 8;
  const u16* gp[6];
#pragma unroll
  for (int seg = 0; seg < 6; seg++) {
    if (seg < 2) gp[seg] = A  + (long)(rowBase + seg * 64 + rloc) * K + cgo;
    else         gp[seg] = Bm + (long)(colBase + (seg - 2) * 64 + rloc) * K + cgo;
  }

  f32x4 acc[4][4] = {};

  auto stage = [&](int buf) {
    char* base = (char*)&lds[buf][0];
#pragma unroll
    for (int seg = 0; seg < 6; seg++)
      GLOAD16(gp[seg], base + seg * 8192 + w * 1024);
  };

  const int NKT = K >> 6;
  stage(0);
#pragma unroll
  for (int seg = 0; seg < 6; seg++) gp[seg] += 64;
  asm volatile("s_waitcnt vmcnt(0)" ::: "memory");
  __builtin_amdgcn_s_barrier();

  for (int kt = 0; kt < NKT; kt++) {
    const int cur = kt & 1;
    if (kt + 1 < NKT) {
      stage(cur ^ 1);
#pragma unroll
      for (int seg = 0; seg < 6; seg++) gp[seg] += 64;
      asm volatile("s_waitcnt vmcnt(6)" ::: "memory");
    } else {
      asm volatile("s_waitcnt vmcnt(0)" ::: "memory");
    }
    __builtin_amdgcn_s_barrier();
    asm volatile("" ::: "memory");

    const char* ab = (const char*)&lds[cur][0] + wm * 8192;
    const char* bb = (const char*)&lds[cur][0] + (2 + wn) * 8192;
    s16x8 af[4][2], bfr[4][2];
#pragma unroll
    for (int m = 0; m < 4; m++)
#pragma unroll
      for (int ks = 0; ks < 2; ks++) {
        int rr = m * 16 + lr;
        int c = ks * 4 + lg;
        af[m][ks]  = *(const s16x8*)(ab + rr * 128 + ((c ^ (rr & 7)) * 16));
        bfr[m][ks] = *(const s16x8*)(bb + rr * 128 + ((c ^ (rr & 7)) * 16));
      }
    __builtin_amdgcn_s_setprio(1);
#pragma unroll
    for (int ks = 0; ks < 2; ks++)
#pragma unroll
      for (int m = 0; m < 4; m++)
#pragma unroll
        for (int n = 0; n < 4; n++)
          acc[m][n] = __builtin_amdgcn_mfma_f32_16x16x32_bf16(af[m][ks], bfr[n][ks], acc[m][n], 0, 0, 0);
    __builtin_amdgcn_s_setprio(0);
    asm volatile("" ::: "memory");
    __builtin_amdgcn_s_barrier();
    asm volatile("" ::: "memory");
  }

#pragma unroll
  for (int m = 0; m < 4; m++)
#pragma unroll
    for (int n = 0; n < 4; n++)
#pragma unroll
      for (int r = 0; r < 4; r++)
        epi_store(0, rowBase + wm * 64 + m * 16 + lg * 4 + r,
                  COFF + colBase + wn * 64 + n * 16 + lr, acc[m][n][r], Oq, Ok, Ov, nullptr);
}

// ---------------------------------------------------------------- GEMM 256x256 — R9 4-phase, unchanged
#define GPHASE(MQ, STG, WAIT)                                               \
  {                                                                         \
    s16x8 af[2][2];                                                         \
    _Pragma("unroll") for (int j = 0; j < 2; j++)                           \
      _Pragma("unroll") for (int ks = 0; ks < 2; ks++) {                    \
        int rr = (MQ) * 32 + j * 16 + lr;                                   \
        int c = ks * 4 + lg;                                                \
        af[j][ks] = *(const s16x8*)(ab + rr * 128 + ((c ^ (rr & 7)) * 16)); \
      }                                                                     \
    STG;                                                                    \
    WAIT;                                                                   \
    asm volatile("" ::: "memory");                                          \
    __builtin_amdgcn_s_barrier();                                           \
    asm volatile("" ::: "memory");                                          \
    __builtin_amdgcn_s_setprio(1);                                          \
    _Pragma("unroll") for (int ks = 0; ks < 2; ks++)                        \
      _Pragma("unroll") for (int j = 0; j < 2; j++)                         \
        _Pragma("unroll") for (int n = 0; n < 4; n++)                       \
          acc[(MQ) * 2 + j][n] = __builtin_amdgcn_mfma_f32_16x16x32_bf16(   \
              af[j][ks], bfr[n][ks], acc[(MQ) * 2 + j][n], 0, 0, 0);        \
    __builtin_amdgcn_s_setprio(0);                                          \
    asm volatile("" ::: "memory");                                          \
    __builtin_amdgcn_s_barrier();                                           \
    asm volatile("" ::: "memory");                                          \
  }

template<int NT, int EPI>
__global__ __launch_bounds__(512) void gemm256(
    const u16* __restrict__ A, const u16* __restrict__ Bm, int K,
    u16* __restrict__ Oq, u16* __restrict__ Ok, u16* __restrict__ Ov, float* __restrict__ Of)
{
  __shared__ __align__(16) u16 lds[2][32768];     // 2 x 64KB
  const int tid = threadIdx.x, l = tid & 63, w = tid >> 6;
  const int lg = l >> 4, lr = l & 15;
  const int wm = w >> 2, wn = w & 3;

  const int nwg = NT * 32;
  const int cpx = nwg >> 3;
  const int bid = blockIdx.x;
  const int swz = (bid & 7) * cpx + (bid >> 3);
  const int by = swz / NT, bx = swz % NT;
  const int rowBase = by * 256, colBase = bx * 256;

  const int rloc = w * 8 + (l >> 3);
  const int cgo  = ((l & 7) ^ (l >> 3)) * 8;
  const u16* gp[8];
#pragma unroll
  for (int seg = 0; seg < 8; seg++) {
    int half = (seg >> 1) & 1;
    int row  = (seg & 1) * 64 + rloc;
    if (seg < 4) gp[seg] = A  + (long)(rowBase + half * 128 + row) * K + cgo;
    else         gp[seg] = Bm + (long)(colBase + half * 128 + row) * K + cgo;
  }

  f32x4 acc[8][4] = {};

  const int NKT = K >> 6;
  {
    char* nb = (char*)&lds[0][0];
#pragma unroll
    for (int seg = 0; seg < 8; seg++)
      GLOAD16(gp[seg], nb + seg * 8192 + w * 1024);
#pragma unroll
    for (int seg = 0; seg < 8; seg++) gp[seg] += 64;
    asm volatile("s_waitcnt vmcnt(0)" ::: "memory");
    __builtin_amdgcn_s_barrier();
    asm volatile("" ::: "memory");
  }

  for (int kt = 0; kt < NKT; kt++) {
    const int cur = kt & 1;
    const bool pre = (kt + 1 < NKT);
    const char* ab = (const char*)&lds[cur][0] + wm * 16384;
    const char* bb = (const char*)&lds[cur][0] + 32768 + (wn >> 1) * 16384;
    char* nb = (char*)&lds[cur ^ 1][0];
    const int rbB = (wn & 1) * 64;

    s16x8 bfr[4][2];
#pragma unroll
    for (int n = 0; n < 4; n++)
#pragma unroll
      for (int ks = 0; ks < 2; ks++) {
        int rb = rbB + n * 16 + lr;
        int c = ks * 4 + lg;
        bfr[n][ks] = *(const s16x8*)(bb + rb * 128 + ((c ^ (rb & 7)) * 16));
      }
    GPHASE(0,
      { if (pre) { GLOAD16(gp[4], nb + 4 * 8192 + w * 1024);
                   GLOAD16(gp[5], nb + 5 * 8192 + w * 1024); } },
      { });
    GPHASE(1,
      { if (pre) { GLOAD16(gp[6], nb + 6 * 8192 + w * 1024);
                   GLOAD16(gp[7], nb + 7 * 8192 + w * 1024); } },
      { if (pre) { asm volatile("s_waitcnt vmcnt(4)" ::: "memory"); }
        else     { asm volatile("s_waitcnt vmcnt(0)" ::: "memory"); } });
    GPHASE(2,
      { if (pre) { GLOAD16(gp[0], nb + 0 * 8192 + w * 1024);
                   GLOAD16(gp[2], nb + 2 * 8192 + w * 1024); } },
      { });
    GPHASE(3,
      { if (pre) { GLOAD16(gp[1], nb + 1 * 8192 + w * 1024);
                   GLOAD16(gp[3], nb + 3 * 8192 + w * 1024); } },
      { if (pre) { asm volatile("s_waitcnt vmcnt(2)" ::: "memory"); } });

    if (pre) {
#pragma unroll
      for (int seg = 0; seg < 8; seg++) gp[seg] += 64;
    }
  }

#pragma unroll
  for (int m = 0; m < 8; m++)
#pragma unroll
    for (int n = 0; n < 4; n++)
#pragma unroll
      for (int r = 0; r < 4; r++)
        epi_store(EPI, rowBase + wm * 128 + m * 16 + lg * 4 + r,
                  colBase + wn * 64 + n * 16 + lr, acc[m][n][r], Oq, Ok, Ov, Of);
}

// ---------------------------------------------------------------- RoPE in-place on Qr, Kr
__global__ void rope_kernel(u16* __restrict__ Qr, u16* __restrict__ Kr)
{
  long gid = (long)blockIdx.x * 256 + threadIdx.x;
  int i = (int)(gid & 63);
  long row = gid >> 6;
  int s;
  u16* p;
  const long qrows = (long)NB * NH * SS;
  if (row < qrows) { s = (int)(row & 2047); p = Qr + row * HD; }
  else             { long r2 = row - qrows; s = (int)(r2 & 2047); p = Kr + r2 * HD; }
  float inv = exp2f(-(float)i * 0.20762050593046015f);   // log2(10000)/64
  float fr = (float)s * inv;
  float c = cosf(fr), sn = sinf(fr);
  float x1 = bf2f(p[i]), x2 = bf2f(p[i + 64]);
  p[i]      = f2bf(x1 * c + x2 * sn);
  p[i + 64] = f2bf(-x1 * sn + x2 * c);
}

// ---------------------------------------------------------------- flash attention (causal, GQA)
// R18 core ({__expf, cvtpk}) + R19: scale pre-folded into Q (no per-tile mul),
// 16-slot K swizzle (conflicts halved).
__global__ __launch_bounds__(512) void attn_fwd(const u16* __restrict__ Qr, const u16* __restrict__ Kr,
                                                const u16* __restrict__ Vt, u16* __restrict__ Y)
{
  __shared__ __align__(16) u16 Ks[2][64 * 128];   // [kv][d]  256B rows, 16KB each
  __shared__ __align__(16) u16 Vs[2][128 * 64];   // [d][kv]  128B rows, 16KB each

  const int tid = threadIdx.x, l = tid & 63, w = tid >> 6;
  const int lq = l & 31, hi = l >> 5;
  const int p = blockIdx.x, h = blockIdx.y, b = blockIdx.z;
  const int kvh = h >> 2;

  const u16* Kh = Kr + ((long)(b * NKV + kvh)) * SS * HD;
  const u16* Vh = Vt + ((long)(b * NKV + kvh)) * HD * SS;

  auto stageK = [&](int buf, int kvb) {
    char* kb = (char*)&Ks[buf][0];
#pragma unroll
    for (int i = 0; i < 2; i++) {
      int L = w * 2048 + i * 1024 + l * 16;
      int r = L >> 8;                              // kv row 0..63
      int cl = (L >> 4) & 15;                      // stored chunk slot
      int cg = (cl ^ r) & 15;                      // 16-slot swizzle
      GLOAD16((const char*)(Kh + (long)(kvb + r) * HD) + cg * 16, kb + w * 2048 + i * 1024);
    }
  };
  auto stageV = [&](int buf, int kvb) {
    char* vb = (char*)&Vs[buf][0];
#pragma unroll
    for (int i = 0; i < 2; i++) {
      int L = w * 2048 + i * 1024 + l * 16;
      int r = L >> 7;                              // d row 0..127
      int cl = (L >> 4) & 7;
      int cg = (cl ^ r) & 7;
      GLOAD16((const char*)(Vh + (long)r * SS + kvb) + cg * 16, vb + w * 2048 + i * 1024);
    }
  };

  for (int job = 0; job < 2; job++) {
    const int qt = job ? p : 7 - p;                // big job first
    const int qRow0 = qt * 256 + w * 32;
    const int qMax = qRow0 + 31;
    const int nT = 4 * qt + 4;
    const int myq = qRow0 + lq;
    const u16* Qh = Qr + (((long)(b * NH + h)) * SS + qRow0) * HD;
    u16* Yh = Y + ((long)b * SS) * DMODEL + h * HD;

    s16x8 qf[8];
#pragma unroll
    for (int kk = 0; kk < 8; kk++)
      qf[kk] = *(const s16x8*)(Qh + (long)lq * HD + kk * 16 + hi * 8);

    float m_run = -1e30f, l_run = 0.f;
    f32x16 oacc[4] = {};                           // row=crow(r,hi)=q, col=lane&31=d

    stageK(0, 0); stageV(0, 0);

    for (int t = 0; t < nT; t++) {
      const int cur = t & 1;
      if (t + 1 < nT) {
        stageK(cur ^ 1, (t + 1) * 64);
        stageV(cur ^ 1, (t + 1) * 64);
        asm volatile("s_waitcnt vmcnt(4)" ::: "memory");
      } else {
        asm volatile("s_waitcnt vmcnt(0)" ::: "memory");
      }
      __builtin_amdgcn_s_barrier();
      asm volatile("" ::: "memory");

      if (t * 64 <= qMax) {
        const char* kb = (const char*)&Ks[cur][0];
        const char* vb = (const char*)&Vs[cur][0];
        f32x16 sacc[2] = {};
#pragma unroll
        for (int kk = 0; kk < 8; kk++) {
          int ch = kk * 2 + hi;
#pragma unroll
          for (int tile = 0; tile < 2; tile++) {
            int rr = tile * 32 + lq;
            int cs = (ch ^ rr) & 15;               // 16-slot swizzle
            s16x8 kf = *(const s16x8*)(kb + rr * 256 + cs * 16);
            sacc[tile] = __builtin_amdgcn_mfma_f32_32x32x16_bf16(kf, qf[kk], sacc[tile], 0, 0, 0);
          }
        }
        const bool full = (t * 64 + 63 <= qRow0);
        float pmax = -1e30f;
#pragma unroll
        for (int tile = 0; tile < 2; tile++)
#pragma unroll
          for (int r = 0; r < 16; r++) {
            int kv = t * 64 + tile * 32 + (r & 3) + 8 * (r >> 2) + 4 * hi;
            float v = sacc[tile][r];               // scale pre-folded into Q
            if (!full && kv > myq) v = -30000.f;
            sacc[tile][r] = v;
            pmax = fmaxf(pmax, v);
          }
        pmax = fmaxf(pmax, __shfl_xor(pmax, 32));
        if (!__all(pmax - m_run <= 8.0f)) {
          float mnew = fmaxf(m_run, pmax);
          float sf = __expf(m_run - mnew);
          m_run = mnew; l_run *= sf;
          int sfi = __builtin_bit_cast(int, sf);
#pragma unroll
          for (int r = 0; r < 16; r++) {
            int qq = (r & 3) + 8 * (r >> 2) + 4 * hi;
            float sfr = __builtin_bit_cast(float, __builtin_amdgcn_ds_bpermute(qq << 2, sfi));
#pragma unroll
            for (int n = 0; n < 4; n++) oacc[n][r] *= sfr;
          }
        }
        float rs = 0.f;
#pragma unroll
        for (int tile = 0; tile < 2; tile++)
#pragma unroll
          for (int r = 0; r < 16; r++) {
            float pv = __expf(sacc[tile][r] - m_run);
            sacc[tile][r] = pv;
            rs += pv;
          }
        rs += __shfl_xor(rs, 32);
        l_run += rs;
        s16x8 pav[4];
#pragma unroll
        for (int tile = 0; tile < 2; tile++) {
          u32 qk[8], sw[8];
#pragma unroll
          for (int j = 0; j < 8; j++) {
            qk[j] = cvtpk(sacc[tile][2 * j], sacc[tile][2 * j + 1]);
            sw[j] = __shfl_xor(qk[j], 32);
          }
          u32x4 f0, f1;
          f0[0] = hi ? sw[2] : qk[0];
          f0[1] = hi ? sw[3] : qk[1];
          f0[2] = hi ? qk[2] : sw[0];
          f0[3] = hi ? qk[3] : sw[1];
          f1[0] = hi ? sw[6] : qk[4];
          f1[1] = hi ? sw[7] : qk[5];
          f1[2] = hi ? qk[6] : sw[4];
          f1[3] = hi ? qk[7] : sw[5];
          pav[tile * 2 + 0] = __builtin_bit_cast(s16x8, f0);
          pav[tile * 2 + 1] = __builtin_bit_cast(s16x8, f1);
        }
#pragma unroll
        for (int n = 0; n < 4; n++) {
          int rr = n * 32 + lq;
#pragma unroll
          for (int kk = 0; kk < 4; kk++) {
            int ch = kk * 2 + hi;
            int cs = (ch ^ rr) & 7;
            s16x8 vf = *(const s16x8*)(vb + rr * 128 + cs * 16);
            oacc[n] = __builtin_amdgcn_mfma_f32_32x32x16_bf16(pav[kk], vf, oacc[n], 0, 0, 0);
          }
        }
      }
      asm volatile("" ::: "memory");
      __builtin_amdgcn_s_barrier();
      asm volatile("" ::: "memory");
    }

    float linv = 1.f / l_run;
    int li = __builtin_bit_cast(int, linv);
#pragma unroll
    for (int r = 0; r < 16; r++) {
      int qq = (r & 3) + 8 * (r >> 2) + 4 * hi;
      float lr_ = __builtin_bit_cast(float, __builtin_amdgcn_ds_bpermute(qq << 2, li));
      u16* yrow = Yh + (long)(qRow0 + qq) * DMODEL;
#pragma unroll
      for (int n = 0; n < 4; n++)
        yrow[n * 32 + lq] = f2bf(oacc[n][r] * lr_);
    }
  }
}

// ---------------------------------------------------------------- launch
extern "C" void kernel_launch(void* const* d_in, const int* in_sizes, int n_in,
                              void* d_out, int out_size, void* d_ws, size_t ws_size,
                              hipStream_t stream) {
  const float* x  = (const float*)d_in[0];
  const float* wq = (const float*)d_in[1];
  const float* wk = (const float*)d_in[2];
  const float* wv = (const float*)d_in[3];
  const float* wo = (const float*)d_in[4];
  float* out = (float*)d_out;
  char* ws = (char*)d_ws;

  u16* Xb   = (u16*)ws;                    // 33,554,432 B  (aliased as Y after qkv gemms)
  u16* Wqkv = (u16*)(ws + 33554432);       // 12,582,912 B
  u16* Wob  = (u16*)(ws + 46137344);       //  8,388,608 B
  u16* Qr   = (u16*)(ws + 54525952);       // 33,554,432 B
  u16* Kr   = (u16*)(ws + 88080384);       //  8,388,608 B
  u16* Vt   = (u16*)(ws + 96468992);       //  8,388,608 B
  u16* Y    = Xb;

  cast_all<<<26624, 256, 0, stream>>>(x, wq, wk, wv, wo, Xb, Wqkv, Wob);
  gemm256<8, 0><<<256, 512, 0, stream>>>(Xb, Wqkv, DMODEL, Qr, Kr, Vt, nullptr);
  gemm128<4, 2048><<<256, 512, 0, stream>>>(Xb, Wqkv + 2048 * 2048, DMODEL, Qr, Kr, Vt);
  rope_kernel<<<40960, 256, 0, stream>>>(Qr, Kr);
  dim3 ag(4, NH, NB);
  attn_fwd<<<ag, 512, 0, stream>>>(Qr, Kr, Vt, Y);
  gemm256<8, 1><<<256, 512, 0, stream>>>(Y, Wob, DMODEL, nullptr, nullptr, nullptr, out);
}

// Round 20
// 334.927 us; speedup vs baseline: 1.0929x; 1.0122x over previous
//
#include <hip/hip_runtime.h>
#include <hip/hip_bf16.h>

typedef short s16x8 __attribute__((ext_vector_type(8)));
typedef float f32x4 __attribute__((ext_vector_type(4)));
typedef float f32x16 __attribute__((ext_vector_type(16)));
typedef unsigned u32;
typedef unsigned u32x4 __attribute__((ext_vector_type(4)));
typedef unsigned short u16;

#define DMODEL 2048
#define NH     16
#define NKV    4
#define HD     128
#define NB     4
#define SS     2048

static __device__ __forceinline__ u16 f2bf(float f) {
  unsigned u = __builtin_bit_cast(unsigned, f);
  u += 0x7fffu + ((u >> 16) & 1u);          // RNE
  return (u16)(u >> 16);
}
static __device__ __forceinline__ float bf2f(u16 h) {
  unsigned u = ((unsigned)h) << 16;
  return __builtin_bit_cast(float, u);
}
static __device__ __forceinline__ u32 cvtpk(float a, float b) {   // a -> lo, b -> hi
  u32 r;
  asm("v_cvt_pk_bf16_f32 %0, %1, %2" : "=v"(r) : "v"(a), "v"(b));
  return r;
}

typedef const __attribute__((address_space(1))) void* gas_p;
typedef __attribute__((address_space(3))) void* las_p;
#define GLOAD16(g, l) __builtin_amdgcn_global_load_lds((gas_p)(const void*)(g), (las_p)(void*)(l), 16, 0, 0)

// ---------------------------------------------------------------- cast: f32 -> bf16
__global__ void cast_all(const float* __restrict__ x,  const float* __restrict__ wq,
                         const float* __restrict__ wk, const float* __restrict__ wv,
                         const float* __restrict__ wo,
                         u16* __restrict__ xb, u16* __restrict__ wqkv, u16* __restrict__ wob)
{
  long gid = (long)blockIdx.x * 256 + threadIdx.x;
  long i = gid * 4;
  const float* src; u16* dst; long off;
  if (i < 16777216L)       { src = x;  dst = xb;             off = i; }
  else if (i < 20971520L)  { src = wq; dst = wqkv;           off = i - 16777216L; }
  else if (i < 22020096L)  { src = wk; dst = wqkv + 4194304; off = i - 20971520L; }
  else if (i < 23068672L)  { src = wv; dst = wqkv + 5242880; off = i - 22020096L; }
  else                     { src = wo; dst = wob;            off = i - 23068672L; }
  float4 v = *(const float4*)(src + off);
  ushort4 o;
  o.x = f2bf(v.x); o.y = f2bf(v.y); o.z = f2bf(v.z); o.w = f2bf(v.w);
  *(ushort4*)(dst + off) = o;
}

// ---------------------------------------------------------------- epilogue scatter (shared)
// Q gets the softmax scale folded in (commutes with RoPE rotation).
static __device__ __forceinline__ void epi_store(int EPI, int row, int col, float v,
    u16* __restrict__ Oq, u16* __restrict__ Ok, u16* __restrict__ Ov, float* __restrict__ Of)
{
  if (EPI == 0) {
    int b = row >> 11, s = row & 2047;
    if (col < 2048) {
      int hh = col >> 7, d = col & 127;
      Oq[(((long)(b * NH + hh)) * SS + s) * HD + d] = f2bf(v * 0.08838834764831845f);
    } else if (col < 2560) {
      int c2 = col - 2048, kh = c2 >> 7, d = c2 & 127;
      Ok[(((long)(b * NKV + kh)) * SS + s) * HD + d] = f2bf(v);
    } else {
      int c2 = col - 2560, kh = c2 >> 7, d = c2 & 127;
      Ov[(((long)(b * NKV + kh)) * HD + d) * SS + s] = f2bf(v);   // V transposed [d][s]
    }
  } else {
    Of[(long)row * DMODEL + col] = v;
  }
}

// ---------------------------------------------------------------- GEMM 128x256 (KV) — R10-verified, + col offset
template<int NTC, int COFF>
__global__ __launch_bounds__(512) void gemm128(
    const u16* __restrict__ A, const u16* __restrict__ Bm, int K,
    u16* __restrict__ Oq, u16* __restrict__ Ok, u16* __restrict__ Ov)
{
  __shared__ __align__(16) u16 lds[2][24576];     // 48KB each
  const int tid = threadIdx.x, l = tid & 63, w = tid >> 6;
  const int lg = l >> 4, lr = l & 15;
  const int wm = w >> 2, wn = w & 3;

  const int nwg = NTC * 64;
  const int cpx = nwg >> 3;
  const int bid = blockIdx.x;
  const int swz = (bid & 7) * cpx + (bid >> 3);   // bijective: nwg % 8 == 0
  const int by = swz / NTC, bx = swz % NTC;
  const int rowBase = by * 128, colBase = bx * 256;

  const int rloc = w * 8 + (l >> 3);
  const int cgo  = ((l & 7) ^ (l >> 3)) * 8;
  const u16* gp[6];
#pragma unroll
  for (int seg = 0; seg < 6; seg++) {
    if (seg < 2) gp[seg] = A  + (long)(rowBase + seg * 64 + rloc) * K + cgo;
    else         gp[seg] = Bm + (long)(colBase + (seg - 2) * 64 + rloc) * K + cgo;
  }

  f32x4 acc[4][4] = {};

  auto stage = [&](int buf) {
    char* base = (char*)&lds[buf][0];
#pragma unroll
    for (int seg = 0; seg < 6; seg++)
      GLOAD16(gp[seg], base + seg * 8192 + w * 1024);
  };

  const int NKT = K >> 6;
  stage(0);
#pragma unroll
  for (int seg = 0; seg < 6; seg++) gp[seg] += 64;
  asm volatile("s_waitcnt vmcnt(0)" ::: "memory");
  __builtin_amdgcn_s_barrier();

  for (int kt = 0; kt < NKT; kt++) {
    const int cur = kt & 1;
    if (kt + 1 < NKT) {
      stage(cur ^ 1);
#pragma unroll
      for (int seg = 0; seg < 6; seg++) gp[seg] += 64;
      asm volatile("s_waitcnt vmcnt(6)" ::: "memory");
    } else {
      asm volatile("s_waitcnt vmcnt(0)" ::: "memory");
    }
    __builtin_amdgcn_s_barrier();
    asm volatile("" ::: "memory");

    const char* ab = (const char*)&lds[cur][0] + wm * 8192;
    const char* bb = (const char*)&lds[cur][0] + (2 + wn) * 8192;
    s16x8 af[4][2], bfr[4][2];
#pragma unroll
    for (int m = 0; m < 4; m++)
#pragma unroll
      for (int ks = 0; ks < 2; ks++) {
        int rr = m * 16 + lr;
        int c = ks * 4 + lg;
        af[m][ks]  = *(const s16x8*)(ab + rr * 128 + ((c ^ (rr & 7)) * 16));
        bfr[m][ks] = *(const s16x8*)(bb + rr * 128 + ((c ^ (rr & 7)) * 16));
      }
    __builtin_amdgcn_s_setprio(1);
#pragma unroll
    for (int ks = 0; ks < 2; ks++)
#pragma unroll
      for (int m = 0; m < 4; m++)
#pragma unroll
        for (int n = 0; n < 4; n++)
          acc[m][n] = __builtin_amdgcn_mfma_f32_16x16x32_bf16(af[m][ks], bfr[n][ks], acc[m][n], 0, 0, 0);
    __builtin_amdgcn_s_setprio(0);
    asm volatile("" ::: "memory");
    __builtin_amdgcn_s_barrier();
    asm volatile("" ::: "memory");
  }

#pragma unroll
  for (int m = 0; m < 4; m++)
#pragma unroll
    for (int n = 0; n < 4; n++)
#pragma unroll
      for (int r = 0; r < 4; r++)
        epi_store(0, rowBase + wm * 64 + m * 16 + lg * 4 + r,
                  COFF + colBase + wn * 64 + n * 16 + lr, acc[m][n][r], Oq, Ok, Ov, nullptr);
}

// ---------------------------------------------------------------- GEMM 256x256 — R9 4-phase, unchanged
#define GPHASE(MQ, STG, WAIT)                                               \
  {                                                                         \
    s16x8 af[2][2];                                                         \
    _Pragma("unroll") for (int j = 0; j < 2; j++)                           \
      _Pragma("unroll") for (int ks = 0; ks < 2; ks++) {                    \
        int rr = (MQ) * 32 + j * 16 + lr;                                   \
        int c = ks * 4 + lg;                                                \
        af[j][ks] = *(const s16x8*)(ab + rr * 128 + ((c ^ (rr & 7)) * 16)); \
      }                                                                     \
    STG;                                                                    \
    WAIT;                                                                   \
    asm volatile("" ::: "memory");                                          \
    __builtin_amdgcn_s_barrier();                                           \
    asm volatile("" ::: "memory");                                          \
    __builtin_amdgcn_s_setprio(1);                                          \
    _Pragma("unroll") for (int ks = 0; ks < 2; ks++)                        \
      _Pragma("unroll") for (int j = 0; j < 2; j++)                         \
        _Pragma("unroll") for (int n = 0; n < 4; n++)                       \
          acc[(MQ) * 2 + j][n] = __builtin_amdgcn_mfma_f32_16x16x32_bf16(   \
              af[j][ks], bfr[n][ks], acc[(MQ) * 2 + j][n], 0, 0, 0);        \
    __builtin_amdgcn_s_setprio(0);                                          \
    asm volatile("" ::: "memory");                                          \
    __builtin_amdgcn_s_barrier();                                           \
    asm volatile("" ::: "memory");                                          \
  }

template<int NT, int EPI>
__global__ __launch_bounds__(512) void gemm256(
    const u16* __restrict__ A, const u16* __restrict__ Bm, int K,
    u16* __restrict__ Oq, u16* __restrict__ Ok, u16* __restrict__ Ov, float* __restrict__ Of)
{
  __shared__ __align__(16) u16 lds[2][32768];     // 2 x 64KB
  const int tid = threadIdx.x, l = tid & 63, w = tid >> 6;
  const int lg = l >> 4, lr = l & 15;
  const int wm = w >> 2, wn = w & 3;

  const int nwg = NT * 32;
  const int cpx = nwg >> 3;
  const int bid = blockIdx.x;
  const int swz = (bid & 7) * cpx + (bid >> 3);
  const int by = swz / NT, bx = swz % NT;
  const int rowBase = by * 256, colBase = bx * 256;

  const int rloc = w * 8 + (l >> 3);
  const int cgo  = ((l & 7) ^ (l >> 3)) * 8;
  const u16* gp[8];
#pragma unroll
  for (int seg = 0; seg < 8; seg++) {
    int half = (seg >> 1) & 1;
    int row  = (seg & 1) * 64 + rloc;
    if (seg < 4) gp[seg] = A  + (long)(rowBase + half * 128 + row) * K + cgo;
    else         gp[seg] = Bm + (long)(colBase + half * 128 + row) * K + cgo;
  }

  f32x4 acc[8][4] = {};

  const int NKT = K >> 6;
  {
    char* nb = (char*)&lds[0][0];
#pragma unroll
    for (int seg = 0; seg < 8; seg++)
      GLOAD16(gp[seg], nb + seg * 8192 + w * 1024);
#pragma unroll
    for (int seg = 0; seg < 8; seg++) gp[seg] += 64;
    asm volatile("s_waitcnt vmcnt(0)" ::: "memory");
    __builtin_amdgcn_s_barrier();
    asm volatile("" ::: "memory");
  }

  for (int kt = 0; kt < NKT; kt++) {
    const int cur = kt & 1;
    const bool pre = (kt + 1 < NKT);
    const char* ab = (const char*)&lds[cur][0] + wm * 16384;
    const char* bb = (const char*)&lds[cur][0] + 32768 + (wn >> 1) * 16384;
    char* nb = (char*)&lds[cur ^ 1][0];
    const int rbB = (wn & 1) * 64;

    s16x8 bfr[4][2];
#pragma unroll
    for (int n = 0; n < 4; n++)
#pragma unroll
      for (int ks = 0; ks < 2; ks++) {
        int rb = rbB + n * 16 + lr;
        int c = ks * 4 + lg;
        bfr[n][ks] = *(const s16x8*)(bb + rb * 128 + ((c ^ (rb & 7)) * 16));
      }
    GPHASE(0,
      { if (pre) { GLOAD16(gp[4], nb + 4 * 8192 + w * 1024);
                   GLOAD16(gp[5], nb + 5 * 8192 + w * 1024); } },
      { });
    GPHASE(1,
      { if (pre) { GLOAD16(gp[6], nb + 6 * 8192 + w * 1024);
                   GLOAD16(gp[7], nb + 7 * 8192 + w * 1024); } },
      { if (pre) { asm volatile("s_waitcnt vmcnt(4)" ::: "memory"); }
        else     { asm volatile("s_waitcnt vmcnt(0)" ::: "memory"); } });
    GPHASE(2,
      { if (pre) { GLOAD16(gp[0], nb + 0 * 8192 + w * 1024);
                   GLOAD16(gp[2], nb + 2 * 8192 + w * 1024); } },
      { });
    GPHASE(3,
      { if (pre) { GLOAD16(gp[1], nb + 1 * 8192 + w * 1024);
                   GLOAD16(gp[3], nb + 3 * 8192 + w * 1024); } },
      { if (pre) { asm volatile("s_waitcnt vmcnt(2)" ::: "memory"); } });

    if (pre) {
#pragma unroll
      for (int seg = 0; seg < 8; seg++) gp[seg] += 64;
    }
  }

#pragma unroll
  for (int m = 0; m < 8; m++)
#pragma unroll
    for (int n = 0; n < 4; n++)
#pragma unroll
      for (int r = 0; r < 4; r++)
        epi_store(EPI, rowBase + wm * 128 + m * 16 + lg * 4 + r,
                  colBase + wn * 64 + n * 16 + lr, acc[m][n][r], Oq, Ok, Ov, Of);
}

// ---------------------------------------------------------------- RoPE in-place on Qr, Kr
__global__ void rope_kernel(u16* __restrict__ Qr, u16* __restrict__ Kr)
{
  long gid = (long)blockIdx.x * 256 + threadIdx.x;
  int i = (int)(gid & 63);
  long row = gid >> 6;
  int s;
  u16* p;
  const long qrows = (long)NB * NH * SS;
  if (row < qrows) { s = (int)(row & 2047); p = Qr + row * HD; }
  else             { long r2 = row - qrows; s = (int)(r2 & 2047); p = Kr + r2 * HD; }
  float inv = exp2f(-(float)i * 0.20762050593046015f);   // log2(10000)/64
  float fr = (float)s * inv;
  float c = cosf(fr), sn = sinf(fr);
  float x1 = bf2f(p[i]), x2 = bf2f(p[i + 64]);
  p[i]      = f2bf(x1 * c + x2 * sn);
  p[i + 64] = f2bf(-x1 * sn + x2 * c);
}

// ---------------------------------------------------------------- flash attention (causal, GQA)
// Best-cell config: 8-slot K swizzle (R18) + scale folded into Q (R19) +
// {__expf, cvt_pk} softmax core (R18).
__global__ __launch_bounds__(512) void attn_fwd(const u16* __restrict__ Qr, const u16* __restrict__ Kr,
                                                const u16* __restrict__ Vt, u16* __restrict__ Y)
{
  __shared__ __align__(16) u16 Ks[2][64 * 128];   // [kv][d]  256B rows, 16KB each
  __shared__ __align__(16) u16 Vs[2][128 * 64];   // [d][kv]  128B rows, 16KB each

  const int tid = threadIdx.x, l = tid & 63, w = tid >> 6;
  const int lq = l & 31, hi = l >> 5;
  const int p = blockIdx.x, h = blockIdx.y, b = blockIdx.z;
  const int kvh = h >> 2;

  const u16* Kh = Kr + ((long)(b * NKV + kvh)) * SS * HD;
  const u16* Vh = Vt + ((long)(b * NKV + kvh)) * HD * SS;

  auto stageK = [&](int buf, int kvb) {
    char* kb = (char*)&Ks[buf][0];
#pragma unroll
    for (int i = 0; i < 2; i++) {
      int L = w * 2048 + i * 1024 + l * 16;
      int r = L >> 8;                              // kv row 0..63
      int cl = (L >> 4) & 15;
      int cg = (cl & 8) | ((cl ^ r) & 7);          // 8-slot swizzle (R15/R18)
      GLOAD16((const char*)(Kh + (long)(kvb + r) * HD) + cg * 16, kb + w * 2048 + i * 1024);
    }
  };
  auto stageV = [&](int buf, int kvb) {
    char* vb = (char*)&Vs[buf][0];
#pragma unroll
    for (int i = 0; i < 2; i++) {
      int L = w * 2048 + i * 1024 + l * 16;
      int r = L >> 7;                              // d row 0..127
      int cl = (L >> 4) & 7;
      int cg = (cl ^ r) & 7;
      GLOAD16((const char*)(Vh + (long)r * SS + kvb) + cg * 16, vb + w * 2048 + i * 1024);
    }
  };

  for (int job = 0; job < 2; job++) {
    const int qt = job ? p : 7 - p;                // big job first
    const int qRow0 = qt * 256 + w * 32;
    const int qMax = qRow0 + 31;
    const int nT = 4 * qt + 4;
    const int myq = qRow0 + lq;
    const u16* Qh = Qr + (((long)(b * NH + h)) * SS + qRow0) * HD;
    u16* Yh = Y + ((long)b * SS) * DMODEL + h * HD;

    s16x8 qf[8];
#pragma unroll
    for (int kk = 0; kk < 8; kk++)
      qf[kk] = *(const s16x8*)(Qh + (long)lq * HD + kk * 16 + hi * 8);

    float m_run = -1e30f, l_run = 0.f;
    f32x16 oacc[4] = {};                           // row=crow(r,hi)=q, col=lane&31=d

    stageK(0, 0); stageV(0, 0);

    for (int t = 0; t < nT; t++) {
      const int cur = t & 1;
      if (t + 1 < nT) {
        stageK(cur ^ 1, (t + 1) * 64);
        stageV(cur ^ 1, (t + 1) * 64);
        asm volatile("s_waitcnt vmcnt(4)" ::: "memory");
      } else {
        asm volatile("s_waitcnt vmcnt(0)" ::: "memory");
      }
      __builtin_amdgcn_s_barrier();
      asm volatile("" ::: "memory");

      if (t * 64 <= qMax) {
        const char* kb = (const char*)&Ks[cur][0];
        const char* vb = (const char*)&Vs[cur][0];
        f32x16 sacc[2] = {};
#pragma unroll
        for (int kk = 0; kk < 8; kk++) {
          int ch = kk * 2 + hi;
#pragma unroll
          for (int tile = 0; tile < 2; tile++) {
            int rr = tile * 32 + lq;
            int cs = (ch & 8) | ((ch ^ rr) & 7);   // 8-slot swizzle
            s16x8 kf = *(const s16x8*)(kb + rr * 256 + cs * 16);
            sacc[tile] = __builtin_amdgcn_mfma_f32_32x32x16_bf16(kf, qf[kk], sacc[tile], 0, 0, 0);
          }
        }
        const bool full = (t * 64 + 63 <= qRow0);
        float pmax = -1e30f;
#pragma unroll
        for (int tile = 0; tile < 2; tile++)
#pragma unroll
          for (int r = 0; r < 16; r++) {
            int kv = t * 64 + tile * 32 + (r & 3) + 8 * (r >> 2) + 4 * hi;
            float v = sacc[tile][r];               // scale pre-folded into Q
            if (!full && kv > myq) v = -30000.f;
            sacc[tile][r] = v;
            pmax = fmaxf(pmax, v);
          }
        pmax = fmaxf(pmax, __shfl_xor(pmax, 32));
        if (!__all(pmax - m_run <= 8.0f)) {
          float mnew = fmaxf(m_run, pmax);
          float sf = __expf(m_run - mnew);
          m_run = mnew; l_run *= sf;
          int sfi = __builtin_bit_cast(int, sf);
#pragma unroll
          for (int r = 0; r < 16; r++) {
            int qq = (r & 3) + 8 * (r >> 2) + 4 * hi;
            float sfr = __builtin_bit_cast(float, __builtin_amdgcn_ds_bpermute(qq << 2, sfi));
#pragma unroll
            for (int n = 0; n < 4; n++) oacc[n][r] *= sfr;
          }
        }
        float rs = 0.f;
#pragma unroll
        for (int tile = 0; tile < 2; tile++)
#pragma unroll
          for (int r = 0; r < 16; r++) {
            float pv = __expf(sacc[tile][r] - m_run);
            sacc[tile][r] = pv;
            rs += pv;
          }
        rs += __shfl_xor(rs, 32);
        l_run += rs;
        s16x8 pav[4];
#pragma unroll
        for (int tile = 0; tile < 2; tile++) {
          u32 qk[8], sw[8];
#pragma unroll
          for (int j = 0; j < 8; j++) {
            qk[j] = cvtpk(sacc[tile][2 * j], sacc[tile][2 * j + 1]);
            sw[j] = __shfl_xor(qk[j], 32);
          }
          u32x4 f0, f1;
          f0[0] = hi ? sw[2] : qk[0];
          f0[1] = hi ? sw[3] : qk[1];
          f0[2] = hi ? qk[2] : sw[0];
          f0[3] = hi ? qk[3] : sw[1];
          f1[0] = hi ? sw[6] : qk[4];
          f1[1] = hi ? sw[7] : qk[5];
          f1[2] = hi ? qk[6] : sw[4];
          f1[3] = hi ? qk[7] : sw[5];
          pav[tile * 2 + 0] = __builtin_bit_cast(s16x8, f0);
          pav[tile * 2 + 1] = __builtin_bit_cast(s16x8, f1);
        }
#pragma unroll
        for (int n = 0; n < 4; n++) {
          int rr = n * 32 + lq;
#pragma unroll
          for (int kk = 0; kk < 4; kk++) {
            int ch = kk * 2 + hi;
            int cs = (ch ^ rr) & 7;
            s16x8 vf = *(const s16x8*)(vb + rr * 128 + cs * 16);
            oacc[n] = __builtin_amdgcn_mfma_f32_32x32x16_bf16(pav[kk], vf, oacc[n], 0, 0, 0);
          }
        }
      }
      asm volatile("" ::: "memory");
      __builtin_amdgcn_s_barrier();
      asm volatile("" ::: "memory");
    }

    float linv = 1.f / l_run;
    int li = __builtin_bit_cast(int, linv);
#pragma unroll
    for (int r = 0; r < 16; r++) {
      int qq = (r & 3) + 8 * (r >> 2) + 4 * hi;
      float lr_ = __builtin_bit_cast(float, __builtin_amdgcn_ds_bpermute(qq << 2, li));
      u16* yrow = Yh + (long)(qRow0 + qq) * DMODEL;
#pragma unroll
      for (int n = 0; n < 4; n++)
        yrow[n * 32 + lq] = f2bf(oacc[n][r] * lr_);
    }
  }
}

// ---------------------------------------------------------------- launch
extern "C" void kernel_launch(void* const* d_in, const int* in_sizes, int n_in,
                              void* d_out, int out_size, void* d_ws, size_t ws_size,
                              hipStream_t stream) {
  const float* x  = (const float*)d_in[0];
  const float* wq = (const float*)d_in[1];
  const float* wk = (const float*)d_in[2];
  const float* wv = (const float*)d_in[3];
  const float* wo = (const float*)d_in[4];
  float* out = (float*)d_out;
  char* ws = (char*)d_ws;

  u16* Xb   = (u16*)ws;                    // 33,554,432 B  (aliased as Y after qkv gemms)
  u16* Wqkv = (u16*)(ws + 33554432);       // 12,582,912 B
  u16* Wob  = (u16*)(ws + 46137344);       //  8,388,608 B
  u16* Qr   = (u16*)(ws + 54525952);       // 33,554,432 B
  u16* Kr   = (u16*)(ws + 88080384);       //  8,388,608 B
  u16* Vt   = (u16*)(ws + 96468992);       //  8,388,608 B
  u16* Y    = Xb;

  cast_all<<<26624, 256, 0, stream>>>(x, wq, wk, wv, wo, Xb, Wqkv, Wob);
  gemm256<8, 0><<<256, 512, 0, stream>>>(Xb, Wqkv, DMODEL, Qr, Kr, Vt, nullptr);
  gemm128<4, 2048><<<256, 512, 0, stream>>>(Xb, Wqkv + 2048 * 2048, DMODEL, Qr, Kr, Vt);
  rope_kernel<<<40960, 256, 0, stream>>>(Qr, Kr);
  dim3 ag(4, NH, NB);
  attn_fwd<<<ag, 512, 0, stream>>>(Qr, Kr, Vt, Y);
  gemm256<8, 1><<<256, 512, 0, stream>>>(Y, Wob, DMODEL, nullptr, nullptr, nullptr, out);
}